// Round 1
// 2232.209 us; speedup vs baseline: 1.2876x; 1.2876x over previous
//
#include <hip/hip_runtime.h>
#include <stdint.h>

// Round 4: FPS VALU-issue reduction (validated arithmetic bit-identical).
//  - 512 threads x 16 points (8 v2f pairs): packed-FP32 (v_pk_add/mul_f32) for
//    the contraction-free distance core -> ~halves phase-1 VALU issue.
//  - lv via fmaxf(fmaxf(.x,.y),lv) (v_max3_f32); first-index recovered once per
//    iteration by a descending equality-overwrite scan (first index wins, exact
//    same winner as the old strict-> bookkeeping).
//  - 8 waves: halves redundant phase-2/DPP issue; partial arrays double-buffered
//    -> ONE __syncthreads per iteration (barrier s separates iter s+1 writes of
//    buf p^1 from iter s-1 reads of buf p^1).
//  - xyz staged to LDS (96 KB) once; per-iter centroid fetch is a broadcast
//    ds_read instead of a dependent L2 scalar load.
//  - group_kernel: unchanged from validated Round 3.

#define NBATCH 8
#define NPTS   8192
#define NCH    128
#define NGROUP 2048
#define NK     24
#define ROWLEN (2 * NCH + 3)   // 259

#define FPS_T  512
#define PPT    16              // points per thread (8 pairs)

typedef float v2f __attribute__((ext_vector_type(2)));

__device__ __forceinline__ float sq3_nofma(float dx, float dy, float dz) {
#pragma clang fp contract(off)
  return dx * dx + dy * dy + dz * dz;
}

// numpy einsum contracted inner loop: acc = a0*b0; acc = fma(a1,b1,acc); acc = fma(a2,b2,acc)
__device__ __forceinline__ float dot3_fma(float ax, float ay, float az,
                                          float bx, float by, float bz) {
  float acc = __fmul_rn(ax, bx);
  acc = __fmaf_rn(ay, by, acc);
  acc = __fmaf_rn(az, bz, acc);
  return acc;
}

__device__ __forceinline__ float ballquery_sqr(float srcSq, float dstSq, float dot) {
#pragma clang fp contract(off)
  return (srcSq + dstSq) - 2.0f * dot;
}

template <int CTRL>
__device__ __forceinline__ float maxdpp(float v) {
  int s = __builtin_amdgcn_update_dpp(__builtin_bit_cast(int, v),
                                      __builtin_bit_cast(int, v),
                                      CTRL, 0xF, 0xF, false);
  return fmaxf(v, __builtin_bit_cast(float, s));
}

__device__ __forceinline__ float readlane_f(float v, int lane) {
  return __builtin_bit_cast(float,
      __builtin_amdgcn_readlane(__builtin_bit_cast(int, v), lane));
}

__global__ __launch_bounds__(FPS_T) void fps_kernel(const float* __restrict__ xyz,
                                                    int* __restrict__ fps_idx) {
  const int b = blockIdx.x;
  const int t = threadIdx.x;
  const int lane = t & 63;
  const int w = t >> 6;                 // 8 waves
  const float* xb = xyz + (size_t)b * NPTS * 3;

  __shared__ float s_xyz[NPTS * 3];     // 96 KB: centroid gather source
  __shared__ float s_v[2][8];           // double-buffered per-wave partials
  __shared__ int   s_i[2][8];

  // stage xyz -> LDS (coalesced float4; consumed only after first barrier)
  {
    const float4* src4 = (const float4*)xb;
    float4* dst4 = (float4*)s_xyz;
    for (int i = t; i < (NPTS * 3) / 4; i += FPS_T) dst4[i] = src4[i];
  }

  // thread t owns CONTIGUOUS points [16t, 16t+16): lane order == index order,
  // wave order == index order -> ballot+ctz keeps np.argmax first-index tie-break.
  const int base = t * PPT;
  v2f px[8], py[8], pz[8], d2[8];
#pragma unroll
  for (int j = 0; j < 8; ++j) {
    const int n0 = base + 2 * j;
    px[j].x = xb[n0 * 3 + 0]; py[j].x = xb[n0 * 3 + 1]; pz[j].x = xb[n0 * 3 + 2];
    px[j].y = xb[n0 * 3 + 3]; py[j].y = xb[n0 * 3 + 4]; pz[j].y = xb[n0 * 3 + 5];
    d2[j].x = 1e10f; d2[j].y = 1e10f;
  }

  float cx = xb[0], cy = xb[1], cz = xb[2];   // centroid 0 = point 0
  if (t == 0) fps_idx[b * NGROUP + 0] = 0;

  for (int s = 1; s < NGROUP; ++s) {
    const int p = s & 1;

    // ---- phase 1: packed min-update + value max (exact, contraction-free) ----
    float lv = -1.0f;
#pragma unroll
    for (int j = 0; j < 8; ++j) {
      v2f dx, dy, dz, dd, nd;
      {
#pragma clang fp contract(off)
        dx = px[j] - cx;                    // v_pk_add_f32 (neg)
        dy = py[j] - cy;
        dz = pz[j] - cz;
        dd = dx * dx + dy * dy + dz * dz;   // 3x pk_mul + 2x pk_add, never fused
      }
      nd.x = fminf(d2[j].x, dd.x);
      nd.y = fminf(d2[j].y, dd.y);
      d2[j] = nd;
      lv = fmaxf(fmaxf(nd.x, nd.y), lv);    // v_max3_f32
    }
    // first-index recovery: descending overwrite -> lowest matching index wins
    int kk = 0;
#pragma unroll
    for (int j = 7; j >= 0; --j) {
      if (d2[j].y == lv) kk = 2 * j + 1;
      if (d2[j].x == lv) kk = 2 * j;
    }
    const int li = base + kk;

    // ---- wave argmax via DPP (value max, then ballot for first index) ----
    float v = lv;
    v = maxdpp<0x111>(v);   // row_shr:1
    v = maxdpp<0x112>(v);   // row_shr:2
    v = maxdpp<0x114>(v);   // row_shr:4
    v = maxdpp<0x118>(v);   // row_shr:8
    v = maxdpp<0x142>(v);   // row_bcast15
    v = maxdpp<0x143>(v);   // row_bcast31
    const float wmax = readlane_f(v, 63);
    const unsigned long long m = __ballot(lv == wmax);
    const int wl = (int)__builtin_ctzll(m);            // lowest lane = lowest index
    const int wli = __builtin_amdgcn_readlane(li, wl);
    if (lane == 0) { s_v[p][w] = wmax; s_i[p][w] = wli; }
    __syncthreads();   // the ONLY barrier: orders buf[p] write->read AND buf[p^1] reuse

    // ---- phase 2: every wave reduces the 8 partials redundantly ----
    float pv = (lane < 8) ? s_v[p][lane] : -1.0f;
    int   pi = (lane < 8) ? s_i[p][lane] : 0;
    float r = pv;
    r = maxdpp<0x111>(r);
    r = maxdpp<0x112>(r);
    r = maxdpp<0x114>(r);
    const float bmax = readlane_f(r, 7);
    const unsigned long long m2 = __ballot(pv == bmax);
    const int wwin = (int)__builtin_ctzll(m2);         // lowest wave = lowest index
    const int bi = __builtin_amdgcn_readlane(pi, wwin);

    if (t == 0) fps_idx[b * NGROUP + s] = bi;

    // next centroid coords: broadcast LDS read (no dependent L2 round-trip)
    const int b3 = bi * 3;
    cx = s_xyz[b3 + 0];
    cy = s_xyz[b3 + 1];
    cz = s_xyz[b3 + 2];
  }
}

__global__ __launch_bounds__(256) void group_kernel(const float* __restrict__ xyz,
                                                    const float* __restrict__ points,
                                                    const int* __restrict__ fps_idx,
                                                    float* __restrict__ out) {
  const int gb = blockIdx.x;        // b*NGROUP + g
  const int b = gb >> 11;
  const int tid = threadIdx.x;
  const float* xb = xyz + (size_t)b * NPTS * 3;
  const float* pb = points + (size_t)b * NPTS * NCH;

  __shared__ int s_idx[NK];

  const int a_idx = fps_idx[gb];
  const float cx = xb[a_idx * 3 + 0];
  const float cy = xb[a_idx * 3 + 1];
  const float cz = xb[a_idx * 3 + 2];
  const float srcSq = sq3_nofma(cx, cy, cz);
  const float R2 = (float)(0.2 * 0.2);

  if (tid < 64) {
    int cnt = 0;
    int first = 0;
    const unsigned long long below = ((unsigned long long)1 << tid) - 1ull;
    for (int chunk = 0; chunk < NPTS / 128; ++chunk) {
      const int n0 = (chunk << 7) + (tid << 1);        // 2 points per lane
      const float* p = xb + (size_t)n0 * 3;            // 24B-aligned
      const float2 A = *(const float2*)(p + 0);        // x0 y0
      const float2 Bv = *(const float2*)(p + 2);       // z0 x1
      const float2 C = *(const float2*)(p + 4);        // y1 z1
      const float x0 = A.x, y0 = A.y, z0 = Bv.x;
      const float x1 = Bv.y, y1 = C.x, z1 = C.y;

      const float sqr0 = ballquery_sqr(srcSq, sq3_nofma(x0, y0, z0),
                                       dot3_fma(cx, cy, cz, x0, y0, z0));
      const float sqr1 = ballquery_sqr(srcSq, sq3_nofma(x1, y1, z1),
                                       dot3_fma(cx, cy, cz, x1, y1, z1));
      const bool ok0 = !(sqr0 > R2);
      const bool ok1 = !(sqr1 > R2);
      const unsigned long long m0 = __ballot(ok0);
      const unsigned long long m1 = __ballot(ok1);
      if (cnt == 0 && (m0 | m1)) {
        const int f0 = m0 ? (int)__builtin_ctzll(m0) : 64;
        const int f1 = m1 ? (int)__builtin_ctzll(m1) : 64;
        first = (f0 <= f1) ? ((chunk << 7) + 2 * f0) : ((chunk << 7) + 2 * f1 + 1);
      }
      const int p0 = cnt + (int)__popcll(m0 & below) + (int)__popcll(m1 & below);
      const int p1 = p0 + (ok0 ? 1 : 0);
      if (ok0 && p0 < NK) s_idx[p0] = n0;
      if (ok1 && p1 < NK) s_idx[p1] = n0 + 1;
      cnt += (int)__popcll(m0) + (int)__popcll(m1);
      if (cnt >= NK) break;
    }
    if (tid >= cnt && tid < NK) s_idx[tid] = first;  // pad with first in-radius index
  }
  __syncthreads();

  // output 0: new_xyz (exact copy of the centroid row)
  if (tid == 0) {
    float* onx = out + (size_t)gb * 3;
    onx[0] = cx; onx[1] = cy; onx[2] = cz;
  }

  // output 1: new_points rows — [points[idx](128) | xyz[idx](3) | points[anchor](128)]
  float* op = out + (size_t)NBATCH * NGROUP * 3 + (size_t)gb * (NK * ROWLEN);
  const float* anchor = pb + (size_t)a_idx * NCH;
  for (int e = tid; e < NK * ROWLEN; e += 256) {
    const int k = e / ROWLEN;
    const int c = e - k * ROWLEN;
    const int si = s_idx[k];
    float v;
    if (c < NCH)            v = pb[(size_t)si * NCH + c];
    else if (c < NCH + 3)   v = xb[si * 3 + (c - NCH)];
    else                    v = anchor[c - (NCH + 3)];
    op[e] = v;
  }
}

extern "C" void kernel_launch(void* const* d_in, const int* in_sizes, int n_in,
                              void* d_out, int out_size, void* d_ws, size_t ws_size,
                              hipStream_t stream) {
  const float* xyz = (const float*)d_in[0];
  const float* points = (const float*)d_in[1];
  float* out = (float*)d_out;
  int* fps_idx = (int*)d_ws;  // 8*2048 ints

  fps_kernel<<<dim3(NBATCH), dim3(FPS_T), 0, stream>>>(xyz, fps_idx);
  group_kernel<<<dim3(NBATCH * NGROUP), dim3(256), 0, stream>>>(xyz, points, fps_idx, out);
}